// Round 1
// baseline (454.460 us; speedup 1.0000x reference)
//
#include <hip/hip_runtime.h>
#include <hip/hip_bf16.h>

typedef __bf16 bf16x8 __attribute__((ext_vector_type(8)));
typedef float f32x4 __attribute__((ext_vector_type(4)));

#define B_ 4
#define S_ 2048
#define D_ 1024
#define H_ 16
#define HD_ 64

// ---------------------------------------------------------------- cvt f32->bf16
__global__ __launch_bounds__(256) void k_cvt(const float* __restrict__ in,
                                             __hip_bfloat16* __restrict__ out,
                                             int n) {
  int i = (blockIdx.x * 256 + threadIdx.x) * 4;
  if (i >= n) return;
  float4 v = *reinterpret_cast<const float4*>(in + i);
  __hip_bfloat16 t[4];
  t[0] = __float2bfloat16(v.x);
  t[1] = __float2bfloat16(v.y);
  t[2] = __float2bfloat16(v.z);
  t[3] = __float2bfloat16(v.w);
  *reinterpret_cast<int2*>(out + i) = *reinterpret_cast<int2*>(t);
}

// ---------------------------------------------------------------- QKV GEMM + RoPE
// C[m][e] = sum_k X[m][k] * W[e][k];  m = b*S+s, e = which*1024 + h*64 + d
// q,k get RoPE; q gets *0.125. Outputs laid out [B,H,S,hd] bf16.
__global__ __launch_bounds__(256) void k_qkv_rope(
    const __hip_bfloat16* __restrict__ X, const __hip_bfloat16* __restrict__ W,
    __hip_bfloat16* __restrict__ Qo, __hip_bfloat16* __restrict__ Ko,
    __hip_bfloat16* __restrict__ Vo) {
  __shared__ __hip_bfloat16 Al[64][40];
  __shared__ __hip_bfloat16 Bl[64][40];
  const int tid = threadIdx.x;
  const int wave = tid >> 6;
  const int lane = tid & 63;
  const int m0 = blockIdx.x * 64;
  const int n0 = blockIdx.y * 64;
  const int srow = tid >> 2;
  const int sk = (tid & 3) * 8;
  f32x4 acc[4] = {};
  for (int k0 = 0; k0 < 1024; k0 += 32) {
    __syncthreads();
    *reinterpret_cast<int4*>(&Al[srow][sk]) =
        *reinterpret_cast<const int4*>(&X[(size_t)(m0 + srow) * 1024 + k0 + sk]);
    *reinterpret_cast<int4*>(&Bl[srow][sk]) =
        *reinterpret_cast<const int4*>(&W[(size_t)(n0 + srow) * 1024 + k0 + sk]);
    __syncthreads();
    bf16x8 af =
        *reinterpret_cast<const bf16x8*>(&Al[wave * 16 + (lane & 15)][(lane >> 4) * 8]);
#pragma unroll
    for (int n = 0; n < 4; ++n) {
      bf16x8 bfr =
          *reinterpret_cast<const bf16x8*>(&Bl[n * 16 + (lane & 15)][(lane >> 4) * 8]);
      acc[n] = __builtin_amdgcn_mfma_f32_16x16x32_bf16(af, bfr, acc[n], 0, 0, 0);
    }
  }
  const int which = n0 >> 10;
  const int h = (n0 >> 6) & 15;
  const int col = lane & 15;
  const int rg = (lane >> 4) * 4;
  if (which == 2) {
#pragma unroll
    for (int n = 0; n < 4; ++n)
#pragma unroll
      for (int r = 0; r < 4; ++r) {
        int m = m0 + wave * 16 + rg + r;
        int b = m >> 11, s = m & (S_ - 1);
        Vo[(((size_t)b * H_ + h) * S_ + s) * HD_ + n * 16 + col] =
            __float2bfloat16(acc[n][r]);
      }
  } else {
    __hip_bfloat16* dst = (which == 0) ? Qo : Ko;
    const float scale = (which == 0) ? 0.125f : 1.0f;
#pragma unroll
    for (int i = 0; i < 2; ++i) {
      int dlo = i * 16 + col;  // 0..31
      float invf = exp2f(-(float)(2 * dlo) * (13.287712379549449f / 64.0f));
#pragma unroll
      for (int r = 0; r < 4; ++r) {
        int m = m0 + wave * 16 + rg + r;
        int b = m >> 11, s = m & (S_ - 1);
        float sn, cs;
        sincosf((float)s * invf, &sn, &cs);
        float lo = acc[i][r], hi = acc[i + 2][r];
        size_t base = (((size_t)b * H_ + h) * S_ + s) * HD_;
        dst[base + dlo] = __float2bfloat16((lo * cs - hi * sn) * scale);
        dst[base + dlo + 32] = __float2bfloat16((hi * cs + lo * sn) * scale);
      }
    }
  }
}

// ---------------------------------------------------------------- flash attention
__global__ __launch_bounds__(256) void k_attn(const __hip_bfloat16* __restrict__ Q,
                                              const __hip_bfloat16* __restrict__ K,
                                              const __hip_bfloat16* __restrict__ V,
                                              __hip_bfloat16* __restrict__ AO) {
  __shared__ __hip_bfloat16 Ql[64][72];
  __shared__ __hip_bfloat16 Kl[64][72];
  __shared__ __hip_bfloat16 Vt[64][72];  // transposed: Vt[d][key]
  __shared__ __hip_bfloat16 Pl[4][16][72];
  const int tid = threadIdx.x;
  const int wave = tid >> 6;
  const int lane = tid & 63;
  const int qt = blockIdx.x;
  const int bh = blockIdx.y;
  const int q0 = qt * 64;
  const size_t base = (size_t)bh * S_ * HD_;
  const int srow = tid >> 2;
  const int sk = (tid & 3) * 8;
  // stage Q tile once
  *reinterpret_cast<int4*>(&Ql[srow][sk]) =
      *reinterpret_cast<const int4*>(&Q[base + (size_t)(q0 + srow) * HD_ + sk]);
  *reinterpret_cast<int4*>(&Ql[srow][sk + 32]) =
      *reinterpret_cast<const int4*>(&Q[base + (size_t)(q0 + srow) * HD_ + sk + 32]);
  const int col = lane & 15;
  const int rg = (lane >> 4) * 4;
  const int qw0 = q0 + wave * 16;
  float m_r[4], l_r[4];
  f32x4 o[4] = {};
#pragma unroll
  for (int r = 0; r < 4; ++r) {
    m_r[r] = -1e30f;
    l_r[r] = 0.0f;
  }
  for (int kt = 0; kt <= qt; ++kt) {
    const int k0 = kt * 64;
    __syncthreads();
    *reinterpret_cast<int4*>(&Kl[srow][sk]) =
        *reinterpret_cast<const int4*>(&K[base + (size_t)(k0 + srow) * HD_ + sk]);
    *reinterpret_cast<int4*>(&Kl[srow][sk + 32]) =
        *reinterpret_cast<const int4*>(&K[base + (size_t)(k0 + srow) * HD_ + sk + 32]);
#pragma unroll
    for (int half = 0; half < 2; ++half) {
      int d0 = sk + half * 32;
      int4 pack =
          *reinterpret_cast<const int4*>(&V[base + (size_t)(k0 + srow) * HD_ + d0]);
      __hip_bfloat16 tmp[8];
      *reinterpret_cast<int4*>(tmp) = pack;
#pragma unroll
      for (int j = 0; j < 8; ++j) Vt[d0 + j][srow] = tmp[j];
    }
    __syncthreads();
    // S = Q K^T  (16 q-rows per wave x 64 keys)
    f32x4 sc[4] = {};
#pragma unroll
    for (int kk = 0; kk < 2; ++kk) {
      bf16x8 af = *reinterpret_cast<const bf16x8*>(
          &Ql[wave * 16 + col][(lane >> 4) * 8 + kk * 32]);
#pragma unroll
      for (int n = 0; n < 4; ++n) {
        bf16x8 bfr = *reinterpret_cast<const bf16x8*>(
            &Kl[n * 16 + col][(lane >> 4) * 8 + kk * 32]);
        sc[n] = __builtin_amdgcn_mfma_f32_16x16x32_bf16(af, bfr, sc[n], 0, 0, 0);
      }
    }
    // causal mask
#pragma unroll
    for (int n = 0; n < 4; ++n)
#pragma unroll
      for (int r = 0; r < 4; ++r) {
        int key = k0 + n * 16 + col;
        int qrow = qw0 + rg + r;
        if (key > qrow) sc[n][r] = -1e30f;
      }
    // online softmax (rows owned redundantly by 16-lane groups)
#pragma unroll
    for (int r = 0; r < 4; ++r) {
      float pm = fmaxf(fmaxf(sc[0][r], sc[1][r]), fmaxf(sc[2][r], sc[3][r]));
#pragma unroll
      for (int msk = 1; msk < 16; msk <<= 1) pm = fmaxf(pm, __shfl_xor(pm, msk));
      float mnew = fmaxf(m_r[r], pm);
      float resc = __expf(m_r[r] - mnew);
      float tsum = 0.0f;
#pragma unroll
      for (int n = 0; n < 4; ++n) {
        float p = __expf(sc[n][r] - mnew);
        sc[n][r] = p;
        tsum += p;
      }
#pragma unroll
      for (int msk = 1; msk < 16; msk <<= 1) tsum += __shfl_xor(tsum, msk);
      l_r[r] = l_r[r] * resc + tsum;
      m_r[r] = mnew;
#pragma unroll
      for (int n2 = 0; n2 < 4; ++n2) o[n2][r] *= resc;
    }
    // P -> LDS (bf16), per-wave buffer
#pragma unroll
    for (int n = 0; n < 4; ++n)
#pragma unroll
      for (int r = 0; r < 4; ++r)
        Pl[wave][rg + r][n * 16 + col] = __float2bfloat16(sc[n][r]);
    __syncthreads();
    // O += P V
#pragma unroll
    for (int kk = 0; kk < 2; ++kk) {
      bf16x8 pf = *reinterpret_cast<const bf16x8*>(
          &Pl[wave][col][(lane >> 4) * 8 + kk * 32]);
#pragma unroll
      for (int n2 = 0; n2 < 4; ++n2) {
        bf16x8 vf = *reinterpret_cast<const bf16x8*>(
            &Vt[n2 * 16 + col][(lane >> 4) * 8 + kk * 32]);
        o[n2] = __builtin_amdgcn_mfma_f32_16x16x32_bf16(pf, vf, o[n2], 0, 0, 0);
      }
    }
  }
  const int b = bh >> 4;
  const int h = bh & 15;
#pragma unroll
  for (int r = 0; r < 4; ++r) {
    float inv = 1.0f / l_r[r];
    int s = qw0 + rg + r;
#pragma unroll
    for (int n2 = 0; n2 < 4; ++n2)
      AO[((size_t)(b * S_ + s)) * D_ + h * HD_ + n2 * 16 + col] =
          __float2bfloat16(o[n2][r] * inv);
  }
}

// ---------------------------------------------------------------- out projection
__global__ __launch_bounds__(256) void k_outproj(const __hip_bfloat16* __restrict__ A,
                                                 const __hip_bfloat16* __restrict__ W,
                                                 float* __restrict__ OUT) {
  __shared__ __hip_bfloat16 Al[64][40];
  __shared__ __hip_bfloat16 Bl[64][40];
  const int tid = threadIdx.x;
  const int wave = tid >> 6;
  const int lane = tid & 63;
  const int m0 = blockIdx.x * 64;
  const int n0 = blockIdx.y * 64;
  const int srow = tid >> 2;
  const int sk = (tid & 3) * 8;
  f32x4 acc[4] = {};
  for (int k0 = 0; k0 < 1024; k0 += 32) {
    __syncthreads();
    *reinterpret_cast<int4*>(&Al[srow][sk]) =
        *reinterpret_cast<const int4*>(&A[(size_t)(m0 + srow) * 1024 + k0 + sk]);
    *reinterpret_cast<int4*>(&Bl[srow][sk]) =
        *reinterpret_cast<const int4*>(&W[(size_t)(n0 + srow) * 1024 + k0 + sk]);
    __syncthreads();
    bf16x8 af =
        *reinterpret_cast<const bf16x8*>(&Al[wave * 16 + (lane & 15)][(lane >> 4) * 8]);
#pragma unroll
    for (int n = 0; n < 4; ++n) {
      bf16x8 bfr =
          *reinterpret_cast<const bf16x8*>(&Bl[n * 16 + (lane & 15)][(lane >> 4) * 8]);
      acc[n] = __builtin_amdgcn_mfma_f32_16x16x32_bf16(af, bfr, acc[n], 0, 0, 0);
    }
  }
  const int col = lane & 15;
  const int rg = (lane >> 4) * 4;
#pragma unroll
  for (int n = 0; n < 4; ++n)
#pragma unroll
    for (int r = 0; r < 4; ++r) {
      int m = m0 + wave * 16 + rg + r;
      OUT[(size_t)m * 1024 + n0 + n * 16 + col] = acc[n][r];
    }
}

// ---------------------------------------------------------------- launcher
extern "C" void kernel_launch(void* const* d_in, const int* in_sizes, int n_in,
                              void* d_out, int out_size, void* d_ws, size_t ws_size,
                              hipStream_t stream) {
  const float* x = (const float*)d_in[0];      // [4,2048,1024]
  const float* wqkv = (const float*)d_in[1];   // [3072,1024]
  const float* wout = (const float*)d_in[2];   // [1024,1024]
  float* out = (float*)d_out;

  char* ws = (char*)d_ws;
  const size_t SZ_X = (size_t)B_ * S_ * D_ * 2;        // 16.78 MB
  const size_t SZ_WQKV = (size_t)3 * D_ * D_ * 2;      // 6.29 MB
  const size_t SZ_WOUT = (size_t)D_ * D_ * 2;          // 2.10 MB
  const size_t SZ_T = (size_t)B_ * H_ * S_ * HD_ * 2;  // 16.78 MB
  __hip_bfloat16* xb = (__hip_bfloat16*)(ws);
  __hip_bfloat16* wqkvb = (__hip_bfloat16*)(ws + SZ_X);
  __hip_bfloat16* woutb = (__hip_bfloat16*)(ws + SZ_X + SZ_WQKV);
  __hip_bfloat16* qws = (__hip_bfloat16*)(ws + SZ_X + SZ_WQKV + SZ_WOUT);
  __hip_bfloat16* kws = (__hip_bfloat16*)(ws + SZ_X + SZ_WQKV + SZ_WOUT + SZ_T);
  __hip_bfloat16* vws = (__hip_bfloat16*)(ws + SZ_X + SZ_WQKV + SZ_WOUT + 2 * SZ_T);
  __hip_bfloat16* aob = (__hip_bfloat16*)(ws + SZ_X + SZ_WQKV + SZ_WOUT + 3 * SZ_T);

  const int NX = B_ * S_ * D_;
  const int NW1 = 3 * D_ * D_;
  const int NW2 = D_ * D_;
  k_cvt<<<NX / 1024, 256, 0, stream>>>(x, xb, NX);
  k_cvt<<<NW1 / 1024, 256, 0, stream>>>(wqkv, wqkvb, NW1);
  k_cvt<<<NW2 / 1024, 256, 0, stream>>>(wout, woutb, NW2);

  k_qkv_rope<<<dim3(128, 48), 256, 0, stream>>>(xb, wqkvb, qws, kws, vws);
  k_attn<<<dim3(S_ / 64, B_ * H_), 256, 0, stream>>>(qws, kws, vws, aob);
  k_outproj<<<dim3(128, 16), 256, 0, stream>>>(aob, woutb, out);
}

// Round 2
// 292.983 us; speedup vs baseline: 1.5511x; 1.5511x over previous
//
#include <hip/hip_runtime.h>
#include <hip/hip_bf16.h>

typedef __bf16 bf16x8 __attribute__((ext_vector_type(8)));
typedef float f32x4 __attribute__((ext_vector_type(4)));
typedef __hip_bfloat16 bf16;

#define B_ 4
#define S_ 2048
#define D_ 1024
#define H_ 16
#define HD_ 64

__device__ __forceinline__ void gload16(const bf16* g, bf16* l) {
  __builtin_amdgcn_global_load_lds(
      (const __attribute__((address_space(1))) unsigned int*)g,
      (__attribute__((address_space(3))) unsigned int*)l, 16, 0, 0);
}

// ---------------------------------------------------------------- cvt f32->bf16
__global__ __launch_bounds__(256) void k_cvt(const float* __restrict__ in,
                                             bf16* __restrict__ out, int n) {
  int i = (blockIdx.x * 256 + threadIdx.x) * 4;
  if (i >= n) return;
  float4 v = *reinterpret_cast<const float4*>(in + i);
  alignas(8) bf16 t[4];
  t[0] = __float2bfloat16(v.x);
  t[1] = __float2bfloat16(v.y);
  t[2] = __float2bfloat16(v.z);
  t[3] = __float2bfloat16(v.w);
  *reinterpret_cast<uint2*>(out + i) = *reinterpret_cast<uint2*>(t);
}

// ---------------------------------------------------------------- QKV GEMM (128x128) + RoPE
// C[m][e] = sum_k X[m][k]*W[e][k]. e segments: q(0..1023) k(1024..2047) v(2048..3071)
// Q,K -> [bh][s][d] bf16 (RoPE applied, q*0.125). V -> TRANSPOSED [bh][d][s].
__global__ __launch_bounds__(256) void k_qkv(const bf16* __restrict__ X,
                                             const bf16* __restrict__ W,
                                             bf16* __restrict__ Qw,
                                             bf16* __restrict__ Kw,
                                             bf16* __restrict__ Vtw) {
  __shared__ bf16 Al[128 * 32];
  __shared__ bf16 Bl[128 * 32];
  const int tid = threadIdx.x;
  const int wave = tid >> 6, lane = tid & 63, col = lane & 15, g = lane >> 4;
  const int m0 = blockIdx.x * 128, n0 = blockIdx.y * 128;
  const int wrow = (wave >> 1) * 64, wcol = (wave & 1) * 64;
  const bf16* ga = X + (size_t)(m0 + (tid >> 2)) * 1024 + (tid & 3) * 8;
  const bf16* gb = W + (size_t)(n0 + (tid >> 2)) * 1024 + (tid & 3) * 8;
  bf16* la = Al + (tid >> 2) * 32 + (tid & 3) * 8;
  bf16* lb = Bl + (tid >> 2) * 32 + (tid & 3) * 8;
  f32x4 acc[4][4] = {};
  for (int k0 = 0; k0 < 1024; k0 += 32) {
    __syncthreads();
    gload16(ga + k0, la);
    gload16(ga + k0 + 64 * 1024, la + 64 * 32);
    gload16(gb + k0, lb);
    gload16(gb + k0 + 64 * 1024, lb + 64 * 32);
    __syncthreads();
    bf16x8 af[4], bfr[4];
#pragma unroll
    for (int m = 0; m < 4; ++m)
      af[m] = *reinterpret_cast<const bf16x8*>(&Al[(wrow + m * 16 + col) * 32 + g * 8]);
#pragma unroll
    for (int n = 0; n < 4; ++n)
      bfr[n] = *reinterpret_cast<const bf16x8*>(&Bl[(wcol + n * 16 + col) * 32 + g * 8]);
#pragma unroll
    for (int m = 0; m < 4; ++m)
#pragma unroll
      for (int n = 0; n < 4; ++n)
        acc[m][n] =
            __builtin_amdgcn_mfma_f32_16x16x32_bf16(af[m], bfr[n], acc[m][n], 0, 0, 0);
  }
  const int e0 = n0 + wcol;
  const int which = e0 >> 10;
  const int h = (e0 >> 6) & 15;
  if (which == 2) {
#pragma unroll
    for (int m = 0; m < 4; ++m) {
      int mg = m0 + wrow + m * 16 + g * 4;
      int b = mg >> 11, s = mg & 2047;
#pragma unroll
      for (int n = 0; n < 4; ++n) {
        int d = n * 16 + col;
        alignas(8) bf16 t[4];
#pragma unroll
        for (int r = 0; r < 4; ++r) t[r] = __float2bfloat16(acc[m][n][r]);
        *reinterpret_cast<uint2*>(&Vtw[((size_t)((b * 16 + h) * 64 + d) << 11) + s]) =
            *reinterpret_cast<uint2*>(t);
      }
    }
  } else {
    bf16* dst = which ? Kw : Qw;
    const float scale = which ? 1.0f : 0.125f;
    const float fexp = -2.0f * 13.287712379549449f / 64.0f;
#pragma unroll
    for (int i = 0; i < 2; ++i) {
      int dlo = i * 16 + col;
      float invf = exp2f(fexp * (float)dlo);
#pragma unroll
      for (int m = 0; m < 4; ++m) {
        int mg = m0 + wrow + m * 16 + g * 4;
        int b = mg >> 11;
        size_t rb = (size_t)(b * 16 + h) << 11;
#pragma unroll
        for (int r = 0; r < 4; ++r) {
          int s = (mg + r) & 2047;
          float sn, cs;
          __sincosf((float)s * invf, &sn, &cs);
          float lo = acc[m][i][r] * scale, hi = acc[m][i + 2][r] * scale;
          dst[((rb + s) << 6) + dlo] = __float2bfloat16(lo * cs - hi * sn);
          dst[((rb + s) << 6) + dlo + 32] = __float2bfloat16(hi * cs + lo * sn);
        }
      }
    }
  }
}

// ---------------------------------------------------------------- flash attention
// Swapped QK^T: sc = mfma(K,Q) -> lane holds S[key][q] for ONE q (col=lane&15).
// V comes in pre-transposed [bh][d][s]. P round-trips wave-private LDS (no barrier).
__global__ __launch_bounds__(256) void k_attn(const bf16* __restrict__ Q,
                                              const bf16* __restrict__ K,
                                              const bf16* __restrict__ Vt,
                                              bf16* __restrict__ AO) {
  __shared__ bf16 Ql[64][72];
  __shared__ bf16 Kl[64][72];
  __shared__ bf16 Vl[64][72];  // [d][key]
  __shared__ bf16 Pl[4][16][72];
  const int tid = threadIdx.x;
  const int wave = tid >> 6, lane = tid & 63, col = lane & 15, g = lane >> 4;
  const int qt = blockIdx.x, bh = blockIdx.y;
  const int q0 = qt * 64;
  const size_t base = (size_t)bh << 17;
  const int r0 = tid >> 3, c0 = (tid & 7) * 8;
  // stage Q tile once
  *reinterpret_cast<int4*>(&Ql[r0][c0]) =
      *reinterpret_cast<const int4*>(&Q[base + (size_t)(q0 + r0) * 64 + c0]);
  *reinterpret_cast<int4*>(&Ql[r0 + 32][c0]) =
      *reinterpret_cast<const int4*>(&Q[base + (size_t)(q0 + r0 + 32) * 64 + c0]);
  const int q = q0 + wave * 16 + col;  // this lane's q-row (for scores)
  float m_s = -1e30f, l_s = 0.0f;
  f32x4 o[4] = {};
  for (int kt = 0; kt <= qt; ++kt) {
    const int k0 = kt * 64;
    __syncthreads();
    *reinterpret_cast<int4*>(&Kl[r0][c0]) =
        *reinterpret_cast<const int4*>(&K[base + (size_t)(k0 + r0) * 64 + c0]);
    *reinterpret_cast<int4*>(&Kl[r0 + 32][c0]) =
        *reinterpret_cast<const int4*>(&K[base + (size_t)(k0 + r0 + 32) * 64 + c0]);
    *reinterpret_cast<int4*>(&Vl[r0][c0]) =
        *reinterpret_cast<const int4*>(&Vt[base + (size_t)r0 * 2048 + k0 + c0]);
    *reinterpret_cast<int4*>(&Vl[r0 + 32][c0]) =
        *reinterpret_cast<const int4*>(&Vt[base + (size_t)(r0 + 32) * 2048 + k0 + c0]);
    __syncthreads();
    // S^T tile: sc[n][r] = S[key = k0+n*16+g*4+r][q]
    f32x4 sc[4] = {};
#pragma unroll
    for (int kk = 0; kk < 2; ++kk) {
      bf16x8 qf = *reinterpret_cast<const bf16x8*>(&Ql[wave * 16 + col][g * 8 + kk * 32]);
#pragma unroll
      for (int n = 0; n < 4; ++n) {
        bf16x8 kf = *reinterpret_cast<const bf16x8*>(&Kl[n * 16 + col][g * 8 + kk * 32]);
        sc[n] = __builtin_amdgcn_mfma_f32_16x16x32_bf16(kf, qf, sc[n], 0, 0, 0);
      }
    }
    // mask + in-lane max
    float pm = -1e30f;
#pragma unroll
    for (int n = 0; n < 4; ++n)
#pragma unroll
      for (int r = 0; r < 4; ++r) {
        int key = k0 + n * 16 + g * 4 + r;
        if (key > q) sc[n][r] = -1e30f;
        pm = fmaxf(pm, sc[n][r]);
      }
    pm = fmaxf(pm, __shfl_xor(pm, 16));
    pm = fmaxf(pm, __shfl_xor(pm, 32));
    float mnew = fmaxf(m_s, pm);
    float resc = __expf(m_s - mnew);
    float tsum = 0.0f;
#pragma unroll
    for (int n = 0; n < 4; ++n)
#pragma unroll
      for (int r = 0; r < 4; ++r) {
        float p = __expf(sc[n][r] - mnew);
        sc[n][r] = p;
        tsum += p;
      }
    tsum += __shfl_xor(tsum, 16);
    tsum += __shfl_xor(tsum, 32);
    l_s = l_s * resc + tsum;
    m_s = mnew;
    // rescale O rows (row q' = q0+wave*16+g*4+r lives at lanes col=g*4+r)
#pragma unroll
    for (int r = 0; r < 4; ++r) {
      float rr = __shfl(resc, (lane & 48) | (g * 4 + r));
#pragma unroll
      for (int n2 = 0; n2 < 4; ++n2) o[n2][r] *= rr;
    }
    // P -> wave-private LDS, packed 8B
#pragma unroll
    for (int n = 0; n < 4; ++n) {
      alignas(8) bf16 t[4];
#pragma unroll
      for (int r = 0; r < 4; ++r) t[r] = __float2bfloat16(sc[n][r]);
      *reinterpret_cast<uint2*>(&Pl[wave][col][n * 16 + g * 4]) =
          *reinterpret_cast<uint2*>(t);
    }
    // O += P V   (no barrier: Pl is wave-private)
#pragma unroll
    for (int kk = 0; kk < 2; ++kk) {
      bf16x8 pf = *reinterpret_cast<const bf16x8*>(&Pl[wave][col][g * 8 + kk * 32]);
#pragma unroll
      for (int n2 = 0; n2 < 4; ++n2) {
        bf16x8 vf = *reinterpret_cast<const bf16x8*>(&Vl[n2 * 16 + col][g * 8 + kk * 32]);
        o[n2] = __builtin_amdgcn_mfma_f32_16x16x32_bf16(pf, vf, o[n2], 0, 0, 0);
      }
    }
  }
  const int b = bh >> 4, h = bh & 15;
#pragma unroll
  for (int r = 0; r < 4; ++r) {
    float inv = 1.0f / __shfl(l_s, (lane & 48) | (g * 4 + r));
    int s = q0 + wave * 16 + g * 4 + r;
#pragma unroll
    for (int n2 = 0; n2 < 4; ++n2)
      AO[((size_t)(b * 2048 + s) << 10) + h * 64 + n2 * 16 + col] =
          __float2bfloat16(o[n2][r] * inv);
  }
}

// ---------------------------------------------------------------- out projection (128x128)
__global__ __launch_bounds__(256) void k_outproj(const bf16* __restrict__ A,
                                                 const bf16* __restrict__ W,
                                                 float* __restrict__ OUT) {
  __shared__ bf16 Al[128 * 32];
  __shared__ bf16 Bl[128 * 32];
  const int tid = threadIdx.x;
  const int wave = tid >> 6, lane = tid & 63, col = lane & 15, g = lane >> 4;
  const int m0 = blockIdx.x * 128, n0 = blockIdx.y * 128;
  const int wrow = (wave >> 1) * 64, wcol = (wave & 1) * 64;
  const bf16* ga = A + (size_t)(m0 + (tid >> 2)) * 1024 + (tid & 3) * 8;
  const bf16* gb = W + (size_t)(n0 + (tid >> 2)) * 1024 + (tid & 3) * 8;
  bf16* la = Al + (tid >> 2) * 32 + (tid & 3) * 8;
  bf16* lb = Bl + (tid >> 2) * 32 + (tid & 3) * 8;
  f32x4 acc[4][4] = {};
  for (int k0 = 0; k0 < 1024; k0 += 32) {
    __syncthreads();
    gload16(ga + k0, la);
    gload16(ga + k0 + 64 * 1024, la + 64 * 32);
    gload16(gb + k0, lb);
    gload16(gb + k0 + 64 * 1024, lb + 64 * 32);
    __syncthreads();
    bf16x8 af[4], bfr[4];
#pragma unroll
    for (int m = 0; m < 4; ++m)
      af[m] = *reinterpret_cast<const bf16x8*>(&Al[(wrow + m * 16 + col) * 32 + g * 8]);
#pragma unroll
    for (int n = 0; n < 4; ++n)
      bfr[n] = *reinterpret_cast<const bf16x8*>(&Bl[(wcol + n * 16 + col) * 32 + g * 8]);
#pragma unroll
    for (int m = 0; m < 4; ++m)
#pragma unroll
      for (int n = 0; n < 4; ++n)
        acc[m][n] =
            __builtin_amdgcn_mfma_f32_16x16x32_bf16(af[m], bfr[n], acc[m][n], 0, 0, 0);
  }
#pragma unroll
  for (int m = 0; m < 4; ++m)
#pragma unroll
    for (int n = 0; n < 4; ++n)
#pragma unroll
      for (int r = 0; r < 4; ++r)
        OUT[(size_t)(m0 + wrow + m * 16 + g * 4 + r) * 1024 + n0 + wcol + n * 16 + col] =
            acc[m][n][r];
}

// ---------------------------------------------------------------- launcher
extern "C" void kernel_launch(void* const* d_in, const int* in_sizes, int n_in,
                              void* d_out, int out_size, void* d_ws, size_t ws_size,
                              hipStream_t stream) {
  const float* x = (const float*)d_in[0];
  const float* wqkv = (const float*)d_in[1];
  const float* wout = (const float*)d_in[2];
  float* out = (float*)d_out;

  char* ws = (char*)d_ws;
  const size_t SZ_X = (size_t)B_ * S_ * D_ * 2;
  const size_t SZ_WQKV = (size_t)3 * D_ * D_ * 2;
  const size_t SZ_WOUT = (size_t)D_ * D_ * 2;
  const size_t SZ_T = (size_t)B_ * H_ * S_ * HD_ * 2;
  bf16* xb = (bf16*)(ws);
  bf16* wqkvb = (bf16*)(ws + SZ_X);
  bf16* woutb = (bf16*)(ws + SZ_X + SZ_WQKV);
  bf16* qws = (bf16*)(ws + SZ_X + SZ_WQKV + SZ_WOUT);
  bf16* kws = (bf16*)(ws + SZ_X + SZ_WQKV + SZ_WOUT + SZ_T);
  bf16* vtws = (bf16*)(ws + SZ_X + SZ_WQKV + SZ_WOUT + 2 * SZ_T);
  bf16* aob = (bf16*)(ws + SZ_X + SZ_WQKV + SZ_WOUT + 3 * SZ_T);

  const int NX = B_ * S_ * D_;
  const int NW1 = 3 * D_ * D_;
  const int NW2 = D_ * D_;
  k_cvt<<<NX / 1024, 256, 0, stream>>>(x, xb, NX);
  k_cvt<<<NW1 / 1024, 256, 0, stream>>>(wqkv, wqkvb, NW1);
  k_cvt<<<NW2 / 1024, 256, 0, stream>>>(wout, woutb, NW2);

  k_qkv<<<dim3(64, 24), 256, 0, stream>>>(xb, wqkvb, qws, kws, vtws);
  k_attn<<<dim3(S_ / 64, B_ * H_), 256, 0, stream>>>(qws, kws, vtws, aob);
  k_outproj<<<dim3(64, 8), 256, 0, stream>>>(aob, woutb, out);
}

// Round 3
// 235.725 us; speedup vs baseline: 1.9279x; 1.2429x over previous
//
#include <hip/hip_runtime.h>
#include <hip/hip_bf16.h>

typedef __bf16 bf16x8 __attribute__((ext_vector_type(8)));
typedef float f32x4 __attribute__((ext_vector_type(4)));
typedef __hip_bfloat16 bf16;

#define B_ 4
#define S_ 2048
#define D_ 1024
#define H_ 16
#define HD_ 64

__device__ __forceinline__ void gload16(const bf16* g, bf16* l) {
  __builtin_amdgcn_global_load_lds(
      (const __attribute__((address_space(1))) unsigned int*)g,
      (__attribute__((address_space(3))) unsigned int*)l, 16, 0, 0);
}

// ---------------------------------------------------------------- cvt f32->bf16
__global__ __launch_bounds__(256) void k_cvt(const float* __restrict__ in,
                                             bf16* __restrict__ out, int n) {
  int i = (blockIdx.x * 256 + threadIdx.x) * 4;
  if (i >= n) return;
  float4 v = *reinterpret_cast<const float4*>(in + i);
  alignas(8) bf16 t[4];
  t[0] = __float2bfloat16(v.x);
  t[1] = __float2bfloat16(v.y);
  t[2] = __float2bfloat16(v.z);
  t[3] = __float2bfloat16(v.w);
  *reinterpret_cast<uint2*>(out + i) = *reinterpret_cast<uint2*>(t);
}

// ---------------------------------------------------------------- QKV GEMM (128x128) + RoPE
// Q gets RoPE and *0.125*log2(e) (softmax later runs in exp2 domain).
// K gets RoPE. V stored TRANSPOSED [bh][d][s].
__global__ __launch_bounds__(256) void k_qkv(const bf16* __restrict__ X,
                                             const bf16* __restrict__ W,
                                             bf16* __restrict__ Qw,
                                             bf16* __restrict__ Kw,
                                             bf16* __restrict__ Vtw) {
  __shared__ bf16 Al[128 * 32];
  __shared__ bf16 Bl[128 * 32];
  const int tid = threadIdx.x;
  const int wave = tid >> 6, lane = tid & 63, col = lane & 15, g = lane >> 4;
  const int m0 = blockIdx.x * 128, n0 = blockIdx.y * 128;
  const int wrow = (wave >> 1) * 64, wcol = (wave & 1) * 64;
  const bf16* ga = X + (size_t)(m0 + (tid >> 2)) * 1024 + (tid & 3) * 8;
  const bf16* gb = W + (size_t)(n0 + (tid >> 2)) * 1024 + (tid & 3) * 8;
  bf16* la = Al + (tid >> 2) * 32 + (tid & 3) * 8;
  bf16* lb = Bl + (tid >> 2) * 32 + (tid & 3) * 8;
  f32x4 acc[4][4] = {};
  for (int k0 = 0; k0 < 1024; k0 += 32) {
    __syncthreads();
    gload16(ga + k0, la);
    gload16(ga + k0 + 64 * 1024, la + 64 * 32);
    gload16(gb + k0, lb);
    gload16(gb + k0 + 64 * 1024, lb + 64 * 32);
    __syncthreads();
    bf16x8 af[4], bfr[4];
#pragma unroll
    for (int m = 0; m < 4; ++m)
      af[m] = *reinterpret_cast<const bf16x8*>(&Al[(wrow + m * 16 + col) * 32 + g * 8]);
#pragma unroll
    for (int n = 0; n < 4; ++n)
      bfr[n] = *reinterpret_cast<const bf16x8*>(&Bl[(wcol + n * 16 + col) * 32 + g * 8]);
#pragma unroll
    for (int m = 0; m < 4; ++m)
#pragma unroll
      for (int n = 0; n < 4; ++n)
        acc[m][n] =
            __builtin_amdgcn_mfma_f32_16x16x32_bf16(af[m], bfr[n], acc[m][n], 0, 0, 0);
  }
  const int e0 = n0 + wcol;
  const int which = e0 >> 10;
  const int h = (e0 >> 6) & 15;
  if (which == 2) {
#pragma unroll
    for (int m = 0; m < 4; ++m) {
      int mg = m0 + wrow + m * 16 + g * 4;
      int b = mg >> 11, s = mg & 2047;
#pragma unroll
      for (int n = 0; n < 4; ++n) {
        int d = n * 16 + col;
        alignas(8) bf16 t[4];
#pragma unroll
        for (int r = 0; r < 4; ++r) t[r] = __float2bfloat16(acc[m][n][r]);
        *reinterpret_cast<uint2*>(&Vtw[((size_t)((b * 16 + h) * 64 + d) << 11) + s]) =
            *reinterpret_cast<uint2*>(t);
      }
    }
  } else {
    bf16* dst = which ? Kw : Qw;
    const float scale = which ? 1.0f : 0.18033688011112042f;  // 0.125*log2(e)
    const float fexp = -2.0f * 13.287712379549449f / 64.0f;
#pragma unroll
    for (int i = 0; i < 2; ++i) {
      int dlo = i * 16 + col;
      float invf = exp2f(fexp * (float)dlo);
#pragma unroll
      for (int m = 0; m < 4; ++m) {
        int mg = m0 + wrow + m * 16 + g * 4;
        int b = mg >> 11;
        size_t rb = (size_t)(b * 16 + h) << 11;
#pragma unroll
        for (int r = 0; r < 4; ++r) {
          int s = (mg + r) & 2047;
          float sn, cs;
          __sincosf((float)s * invf, &sn, &cs);
          float lo = acc[m][i][r] * scale, hi = acc[m][i + 2][r] * scale;
          dst[((rb + s) << 6) + dlo] = __float2bfloat16(lo * cs - hi * sn);
          dst[((rb + s) << 6) + dlo + 32] = __float2bfloat16(hi * cs + lo * sn);
        }
      }
    }
  }
}

// ---------------------------------------------------------------- flash attention
// QBLK=128 (4 waves x 32 q-rows), KVBLK=64. Swapped QK^T -> lane owns q=col.
// Q hoisted to regs; Q LDS region reused as per-wave P buffer.
// Async-stage split: next K/V tile loaded to regs during compute (T14).
__global__ __launch_bounds__(256) void k_attn(const bf16* __restrict__ Q,
                                              const bf16* __restrict__ K,
                                              const bf16* __restrict__ Vt,
                                              bf16* __restrict__ AO) {
  __shared__ bf16 QPl[128][72];  // Q staging, then P buffer (wave-private rows)
  __shared__ bf16 Kl[64][72];
  __shared__ bf16 Vl[64][72];  // [d][key]
  const int tid = threadIdx.x;
  const int wave = tid >> 6, lane = tid & 63, col = lane & 15, g = lane >> 4;
  const int bh = blockIdx.x, qt = blockIdx.y;
  const int q0 = qt * 128;
  const size_t base = (size_t)bh << 17;
  const int r0 = tid >> 3, c0 = (tid & 7) * 8;
  // stage Q tile (128 rows)
#pragma unroll
  for (int i = 0; i < 4; ++i)
    *reinterpret_cast<int4*>(&QPl[r0 + 32 * i][c0]) =
        *reinterpret_cast<const int4*>(&Q[base + (size_t)(q0 + r0 + 32 * i) * 64 + c0]);
  __syncthreads();
  bf16x8 qf[2][2];
#pragma unroll
  for (int m = 0; m < 2; ++m)
#pragma unroll
    for (int kk = 0; kk < 2; ++kk)
      qf[m][kk] = *reinterpret_cast<const bf16x8*>(
          &QPl[wave * 32 + m * 16 + col][g * 8 + kk * 32]);
  float m_s[2] = {-3e38f, -3e38f}, l_s[2] = {0.0f, 0.0f};
  f32x4 o[2][4] = {};
  const int ktlim = 2 * qt + 1;            // block-wide last tile (inclusive)
  const int ktmax = 2 * qt + (wave >> 1);  // this wave's last useful tile
  // prologue: load kt=0 K/V into regs
  int4 kr0 = *reinterpret_cast<const int4*>(&K[base + (size_t)r0 * 64 + c0]);
  int4 kr1 = *reinterpret_cast<const int4*>(&K[base + (size_t)(r0 + 32) * 64 + c0]);
  int4 vr0 = *reinterpret_cast<const int4*>(&Vt[base + (size_t)r0 * 2048 + c0]);
  int4 vr1 = *reinterpret_cast<const int4*>(&Vt[base + (size_t)(r0 + 32) * 2048 + c0]);
  for (int kt = 0; kt <= ktlim; ++kt) {
    const int k0 = kt * 64;
    __syncthreads();
    *reinterpret_cast<int4*>(&Kl[r0][c0]) = kr0;
    *reinterpret_cast<int4*>(&Kl[r0 + 32][c0]) = kr1;
    *reinterpret_cast<int4*>(&Vl[r0][c0]) = vr0;
    *reinterpret_cast<int4*>(&Vl[r0 + 32][c0]) = vr1;
    __syncthreads();
    if (kt < ktlim) {  // issue next tile's loads; latency hides under compute
      const int k1 = k0 + 64;
      kr0 = *reinterpret_cast<const int4*>(&K[base + (size_t)(k1 + r0) * 64 + c0]);
      kr1 = *reinterpret_cast<const int4*>(&K[base + (size_t)(k1 + r0 + 32) * 64 + c0]);
      vr0 = *reinterpret_cast<const int4*>(&Vt[base + (size_t)r0 * 2048 + k1 + c0]);
      vr1 = *reinterpret_cast<const int4*>(&Vt[base + (size_t)(r0 + 32) * 2048 + k1 + c0]);
    }
    if (kt <= ktmax) {
      f32x4 sc[2][4] = {};
      __builtin_amdgcn_s_setprio(1);
#pragma unroll
      for (int kk = 0; kk < 2; ++kk)
#pragma unroll
        for (int n = 0; n < 4; ++n) {
          bf16x8 kf =
              *reinterpret_cast<const bf16x8*>(&Kl[n * 16 + col][g * 8 + kk * 32]);
          sc[0][n] =
              __builtin_amdgcn_mfma_f32_16x16x32_bf16(kf, qf[0][kk], sc[0][n], 0, 0, 0);
          sc[1][n] =
              __builtin_amdgcn_mfma_f32_16x16x32_bf16(kf, qf[1][kk], sc[1][n], 0, 0, 0);
        }
      __builtin_amdgcn_s_setprio(0);
#pragma unroll
      for (int m = 0; m < 2; ++m) {
        const int q = q0 + wave * 32 + m * 16 + col;
        float pm = -3e38f;
        if (k0 + 63 > q0 + wave * 32 + m * 16) {  // wave-uniform: tile touches diagonal
#pragma unroll
          for (int n = 0; n < 4; ++n)
#pragma unroll
            for (int r = 0; r < 4; ++r) {
              int key = k0 + n * 16 + g * 4 + r;
              if (key > q) sc[m][n][r] = -3e38f;
              pm = fmaxf(pm, sc[m][n][r]);
            }
        } else {
#pragma unroll
          for (int n = 0; n < 4; ++n)
#pragma unroll
            for (int r = 0; r < 4; ++r) pm = fmaxf(pm, sc[m][n][r]);
        }
        pm = fmaxf(pm, __shfl_xor(pm, 16));
        pm = fmaxf(pm, __shfl_xor(pm, 32));
        float mnew = fmaxf(m_s[m], pm);
        float resc = exp2f(m_s[m] - mnew);
        float tsum = 0.0f;
#pragma unroll
        for (int n = 0; n < 4; ++n)
#pragma unroll
          for (int r = 0; r < 4; ++r) {
            float p = exp2f(sc[m][n][r] - mnew);
            sc[m][n][r] = p;
            tsum += p;
          }
        tsum += __shfl_xor(tsum, 16);
        tsum += __shfl_xor(tsum, 32);
        l_s[m] = l_s[m] * resc + tsum;
        m_s[m] = mnew;
#pragma unroll
        for (int r = 0; r < 4; ++r) {
          float rr = __shfl(resc, (lane & 48) | (g * 4 + r));
#pragma unroll
          for (int n2 = 0; n2 < 4; ++n2) o[m][n2][r] *= rr;
        }
#pragma unroll
        for (int n = 0; n < 4; ++n) {
          alignas(8) bf16 t[4];
#pragma unroll
          for (int r = 0; r < 4; ++r) t[r] = __float2bfloat16(sc[m][n][r]);
          *reinterpret_cast<uint2*>(&QPl[wave * 32 + m * 16 + col][n * 16 + g * 4]) =
              *reinterpret_cast<uint2*>(t);
        }
      }
      // O += P V   (P in wave-private LDS rows)
      __builtin_amdgcn_s_setprio(1);
#pragma unroll
      for (int kk = 0; kk < 2; ++kk) {
        bf16x8 pf0 =
            *reinterpret_cast<const bf16x8*>(&QPl[wave * 32 + col][g * 8 + kk * 32]);
        bf16x8 pf1 =
            *reinterpret_cast<const bf16x8*>(&QPl[wave * 32 + 16 + col][g * 8 + kk * 32]);
#pragma unroll
        for (int n2 = 0; n2 < 4; ++n2) {
          bf16x8 vf =
              *reinterpret_cast<const bf16x8*>(&Vl[n2 * 16 + col][g * 8 + kk * 32]);
          o[0][n2] = __builtin_amdgcn_mfma_f32_16x16x32_bf16(pf0, vf, o[0][n2], 0, 0, 0);
          o[1][n2] = __builtin_amdgcn_mfma_f32_16x16x32_bf16(pf1, vf, o[1][n2], 0, 0, 0);
        }
      }
      __builtin_amdgcn_s_setprio(0);
    }
  }
  const int b = bh >> 4, h = bh & 15;
#pragma unroll
  for (int m = 0; m < 2; ++m)
#pragma unroll
    for (int r = 0; r < 4; ++r) {
      float inv = 1.0f / __shfl(l_s[m], (lane & 48) | (g * 4 + r));
      int s = q0 + wave * 32 + m * 16 + g * 4 + r;
#pragma unroll
      for (int n2 = 0; n2 < 4; ++n2)
        AO[((size_t)(b * 2048 + s) << 10) + h * 64 + n2 * 16 + col] =
            __float2bfloat16(o[m][n2][r] * inv);
    }
}

// ---------------------------------------------------------------- out projection (128x128)
__global__ __launch_bounds__(256) void k_outproj(const bf16* __restrict__ A,
                                                 const bf16* __restrict__ W,
                                                 float* __restrict__ OUT) {
  __shared__ bf16 Al[128 * 32];
  __shared__ bf16 Bl[128 * 32];
  const int tid = threadIdx.x;
  const int wave = tid >> 6, lane = tid & 63, col = lane & 15, g = lane >> 4;
  const int m0 = blockIdx.x * 128, n0 = blockIdx.y * 128;
  const int wrow = (wave >> 1) * 64, wcol = (wave & 1) * 64;
  const bf16* ga = A + (size_t)(m0 + (tid >> 2)) * 1024 + (tid & 3) * 8;
  const bf16* gb = W + (size_t)(n0 + (tid >> 2)) * 1024 + (tid & 3) * 8;
  bf16* la = Al + (tid >> 2) * 32 + (tid & 3) * 8;
  bf16* lb = Bl + (tid >> 2) * 32 + (tid & 3) * 8;
  f32x4 acc[4][4] = {};
  for (int k0 = 0; k0 < 1024; k0 += 32) {
    __syncthreads();
    gload16(ga + k0, la);
    gload16(ga + k0 + 64 * 1024, la + 64 * 32);
    gload16(gb + k0, lb);
    gload16(gb + k0 + 64 * 1024, lb + 64 * 32);
    __syncthreads();
    bf16x8 af[4], bfr[4];
#pragma unroll
    for (int m = 0; m < 4; ++m)
      af[m] = *reinterpret_cast<const bf16x8*>(&Al[(wrow + m * 16 + col) * 32 + g * 8]);
#pragma unroll
    for (int n = 0; n < 4; ++n)
      bfr[n] = *reinterpret_cast<const bf16x8*>(&Bl[(wcol + n * 16 + col) * 32 + g * 8]);
#pragma unroll
    for (int m = 0; m < 4; ++m)
#pragma unroll
      for (int n = 0; n < 4; ++n)
        acc[m][n] =
            __builtin_amdgcn_mfma_f32_16x16x32_bf16(af[m], bfr[n], acc[m][n], 0, 0, 0);
  }
#pragma unroll
  for (int m = 0; m < 4; ++m)
#pragma unroll
    for (int n = 0; n < 4; ++n)
#pragma unroll
      for (int r = 0; r < 4; ++r)
        OUT[(size_t)(m0 + wrow + m * 16 + g * 4 + r) * 1024 + n0 + wcol + n * 16 + col] =
            acc[m][n][r];
}

// ---------------------------------------------------------------- launcher
extern "C" void kernel_launch(void* const* d_in, const int* in_sizes, int n_in,
                              void* d_out, int out_size, void* d_ws, size_t ws_size,
                              hipStream_t stream) {
  const float* x = (const float*)d_in[0];
  const float* wqkv = (const float*)d_in[1];
  const float* wout = (const float*)d_in[2];
  float* out = (float*)d_out;

  char* ws = (char*)d_ws;
  const size_t SZ_X = (size_t)B_ * S_ * D_ * 2;
  const size_t SZ_WQKV = (size_t)3 * D_ * D_ * 2;
  const size_t SZ_WOUT = (size_t)D_ * D_ * 2;
  const size_t SZ_T = (size_t)B_ * H_ * S_ * HD_ * 2;
  bf16* xb = (bf16*)(ws);
  bf16* wqkvb = (bf16*)(ws + SZ_X);
  bf16* woutb = (bf16*)(ws + SZ_X + SZ_WQKV);
  bf16* qws = (bf16*)(ws + SZ_X + SZ_WQKV + SZ_WOUT);
  bf16* kws = (bf16*)(ws + SZ_X + SZ_WQKV + SZ_WOUT + SZ_T);
  bf16* vtws = (bf16*)(ws + SZ_X + SZ_WQKV + SZ_WOUT + 2 * SZ_T);
  bf16* aob = (bf16*)(ws + SZ_X + SZ_WQKV + SZ_WOUT + 3 * SZ_T);

  const int NX = B_ * S_ * D_;
  const int NW1 = 3 * D_ * D_;
  const int NW2 = D_ * D_;
  k_cvt<<<NX / 1024, 256, 0, stream>>>(x, xb, NX);
  k_cvt<<<NW1 / 1024, 256, 0, stream>>>(wqkv, wqkvb, NW1);
  k_cvt<<<NW2 / 1024, 256, 0, stream>>>(wout, woutb, NW2);

  k_qkv<<<dim3(64, 24), 256, 0, stream>>>(xb, wqkvb, qws, kws, vtws);
  k_attn<<<dim3(B_ * H_, S_ / 128), 256, 0, stream>>>(qws, kws, vtws, aob);
  k_outproj<<<dim3(64, 8), 256, 0, stream>>>(aob, woutb, out);
}

// Round 4
// 206.872 us; speedup vs baseline: 2.1968x; 1.1395x over previous
//
#include <hip/hip_runtime.h>
#include <hip/hip_bf16.h>

typedef __bf16 bf16x8 __attribute__((ext_vector_type(8)));
typedef float f32x4 __attribute__((ext_vector_type(4)));
typedef __hip_bfloat16 bf16;

#define B_ 4
#define S_ 2048
#define D_ 1024
#define H_ 16
#define HD_ 64

__device__ __forceinline__ void gload16(const bf16* g, bf16* l) {
  __builtin_amdgcn_global_load_lds(
      (const __attribute__((address_space(1))) unsigned int*)g,
      (__attribute__((address_space(3))) unsigned int*)l, 16, 0, 0);
}

// ---------------------------------------------------------------- cvt f32->bf16 (fused x, w_qkv, w_out)
#define NX_ (B_ * S_ * D_)
#define NW1_ (3 * D_ * D_)
#define NW2_ (D_ * D_)
__global__ __launch_bounds__(256) void k_cvt3(const float* __restrict__ x,
                                              const float* __restrict__ w1,
                                              const float* __restrict__ w2,
                                              bf16* __restrict__ ox,
                                              bf16* __restrict__ o1,
                                              bf16* __restrict__ o2) {
  int i = (blockIdx.x * 256 + threadIdx.x) * 4;
  const float* in;
  bf16* out;
  if (i < NX_) {
    in = x; out = ox;
  } else if (i < NX_ + NW1_) {
    in = w1; out = o1; i -= NX_;
  } else {
    in = w2; out = o2; i -= NX_ + NW1_;
  }
  float4 v = *reinterpret_cast<const float4*>(in + i);
  alignas(8) bf16 t[4];
  t[0] = __float2bfloat16(v.x);
  t[1] = __float2bfloat16(v.y);
  t[2] = __float2bfloat16(v.z);
  t[3] = __float2bfloat16(v.w);
  *reinterpret_cast<uint2*>(out + i) = *reinterpret_cast<uint2*>(t);
}

// ---------------------------------------------------------------- QKV GEMM (128x128) + RoPE
// Q gets RoPE and *0.125*log2(e) (softmax runs in exp2 domain). K gets RoPE.
// V stored TRANSPOSED [bh][d][s].
__global__ __launch_bounds__(256) void k_qkv(const bf16* __restrict__ X,
                                             const bf16* __restrict__ W,
                                             bf16* __restrict__ Qw,
                                             bf16* __restrict__ Kw,
                                             bf16* __restrict__ Vtw) {
  __shared__ bf16 Al[128 * 32];
  __shared__ bf16 Bl[128 * 32];
  const int tid = threadIdx.x;
  const int wave = tid >> 6, lane = tid & 63, col = lane & 15, g = lane >> 4;
  const int m0 = blockIdx.x * 128, n0 = blockIdx.y * 128;
  const int wrow = (wave >> 1) * 64, wcol = (wave & 1) * 64;
  const bf16* ga = X + (size_t)(m0 + (tid >> 2)) * 1024 + (tid & 3) * 8;
  const bf16* gb = W + (size_t)(n0 + (tid >> 2)) * 1024 + (tid & 3) * 8;
  bf16* la = Al + (tid >> 2) * 32 + (tid & 3) * 8;
  bf16* lb = Bl + (tid >> 2) * 32 + (tid & 3) * 8;
  f32x4 acc[4][4] = {};
  for (int k0 = 0; k0 < 1024; k0 += 32) {
    __syncthreads();
    gload16(ga + k0, la);
    gload16(ga + k0 + 64 * 1024, la + 64 * 32);
    gload16(gb + k0, lb);
    gload16(gb + k0 + 64 * 1024, lb + 64 * 32);
    __syncthreads();
    bf16x8 af[4], bfr[4];
#pragma unroll
    for (int m = 0; m < 4; ++m)
      af[m] = *reinterpret_cast<const bf16x8*>(&Al[(wrow + m * 16 + col) * 32 + g * 8]);
#pragma unroll
    for (int n = 0; n < 4; ++n)
      bfr[n] = *reinterpret_cast<const bf16x8*>(&Bl[(wcol + n * 16 + col) * 32 + g * 8]);
#pragma unroll
    for (int m = 0; m < 4; ++m)
#pragma unroll
      for (int n = 0; n < 4; ++n)
        acc[m][n] =
            __builtin_amdgcn_mfma_f32_16x16x32_bf16(af[m], bfr[n], acc[m][n], 0, 0, 0);
  }
  const int e0 = n0 + wcol;
  const int which = e0 >> 10;
  const int h = (e0 >> 6) & 15;
  if (which == 2) {
#pragma unroll
    for (int m = 0; m < 4; ++m) {
      int mg = m0 + wrow + m * 16 + g * 4;
      int b = mg >> 11, s = mg & 2047;
#pragma unroll
      for (int n = 0; n < 4; ++n) {
        int d = n * 16 + col;
        alignas(8) bf16 t[4];
#pragma unroll
        for (int r = 0; r < 4; ++r) t[r] = __float2bfloat16(acc[m][n][r]);
        *reinterpret_cast<uint2*>(&Vtw[((size_t)((b * 16 + h) * 64 + d) << 11) + s]) =
            *reinterpret_cast<uint2*>(t);
      }
    }
  } else {
    bf16* dst = which ? Kw : Qw;
    const float scale = which ? 1.0f : 0.18033688011112042f;  // 0.125*log2(e)
    const float fexp = -2.0f * 13.287712379549449f / 64.0f;
#pragma unroll
    for (int i = 0; i < 2; ++i) {
      int dlo = i * 16 + col;
      float invf = exp2f(fexp * (float)dlo);
#pragma unroll
      for (int m = 0; m < 4; ++m) {
        int mg = m0 + wrow + m * 16 + g * 4;
        int b = mg >> 11;
        size_t rb = (size_t)(b * 16 + h) << 11;
#pragma unroll
        for (int r = 0; r < 4; ++r) {
          int s = (mg + r) & 2047;
          float sn, cs;
          __sincosf((float)s * invf, &sn, &cs);
          float lo = acc[m][i][r] * scale, hi = acc[m][i + 2][r] * scale;
          dst[((rb + s) << 6) + dlo] = __float2bfloat16(lo * cs - hi * sn);
          dst[((rb + s) << 6) + dlo + 32] = __float2bfloat16(hi * cs + lo * sn);
        }
      }
    }
  }
}

// ---------------------------------------------------------------- flash attention
// QBLK=128 (4 waves x 32 q-rows), KVBLK=64, swapped QK^T (lane owns q=col).
// Diagonal-pair scheduling: block y handles qt=y then qt=15-y (equal work/block).
// Q in regs; Q LDS reused as P buffer. Async-stage K/V via regs (T14).
// Defer-max (T13, THR=8 log2-units).
__global__ __launch_bounds__(256) void k_attn(const bf16* __restrict__ Q,
                                              const bf16* __restrict__ K,
                                              const bf16* __restrict__ Vt,
                                              bf16* __restrict__ AO) {
  __shared__ bf16 QPl[128][72];  // Q staging, then P buffer (wave-private rows)
  __shared__ bf16 Kl[64][72];
  __shared__ bf16 Vl[64][72];  // [d][key]
  const int tid = threadIdx.x;
  const int wave = tid >> 6, lane = tid & 63, col = lane & 15, g = lane >> 4;
  const int bh = blockIdx.x;
  const size_t base = (size_t)bh << 17;
  const int r0 = tid >> 3, c0 = (tid & 7) * 8;
  const int b = bh >> 4, h = bh & 15;
  const int NQT = S_ / 128;
  for (int half = 0; half < 2; ++half) {
    const int qt = half ? (NQT - 1 - blockIdx.y) : blockIdx.y;
    const int q0 = qt * 128;
    __syncthreads();  // protect QPl (P rows of previous half) before restage
#pragma unroll
    for (int i = 0; i < 4; ++i)
      *reinterpret_cast<int4*>(&QPl[r0 + 32 * i][c0]) =
          *reinterpret_cast<const int4*>(&Q[base + (size_t)(q0 + r0 + 32 * i) * 64 + c0]);
    __syncthreads();
    bf16x8 qf[2][2];
#pragma unroll
    for (int m = 0; m < 2; ++m)
#pragma unroll
      for (int kk = 0; kk < 2; ++kk)
        qf[m][kk] = *reinterpret_cast<const bf16x8*>(
            &QPl[wave * 32 + m * 16 + col][g * 8 + kk * 32]);
    float m_s[2] = {-3e38f, -3e38f}, l_s[2] = {0.0f, 0.0f};
    f32x4 o[2][4] = {};
    const int ktlim = 2 * qt + 1;            // block-wide last tile (inclusive)
    const int ktmax = 2 * qt + (wave >> 1);  // this wave's last useful tile
    // prologue: load kt=0 K/V into regs
    int4 kr0 = *reinterpret_cast<const int4*>(&K[base + (size_t)r0 * 64 + c0]);
    int4 kr1 = *reinterpret_cast<const int4*>(&K[base + (size_t)(r0 + 32) * 64 + c0]);
    int4 vr0 = *reinterpret_cast<const int4*>(&Vt[base + (size_t)r0 * 2048 + c0]);
    int4 vr1 = *reinterpret_cast<const int4*>(&Vt[base + (size_t)(r0 + 32) * 2048 + c0]);
    for (int kt = 0; kt <= ktlim; ++kt) {
      const int k0 = kt * 64;
      __syncthreads();
      *reinterpret_cast<int4*>(&Kl[r0][c0]) = kr0;
      *reinterpret_cast<int4*>(&Kl[r0 + 32][c0]) = kr1;
      *reinterpret_cast<int4*>(&Vl[r0][c0]) = vr0;
      *reinterpret_cast<int4*>(&Vl[r0 + 32][c0]) = vr1;
      __syncthreads();
      if (kt < ktlim) {  // issue next tile's loads; latency hides under compute
        const int k1 = k0 + 64;
        kr0 = *reinterpret_cast<const int4*>(&K[base + (size_t)(k1 + r0) * 64 + c0]);
        kr1 = *reinterpret_cast<const int4*>(&K[base + (size_t)(k1 + r0 + 32) * 64 + c0]);
        vr0 = *reinterpret_cast<const int4*>(&Vt[base + (size_t)r0 * 2048 + k1 + c0]);
        vr1 =
            *reinterpret_cast<const int4*>(&Vt[base + (size_t)(r0 + 32) * 2048 + k1 + c0]);
      }
      if (kt <= ktmax) {
        f32x4 sc[2][4] = {};
        __builtin_amdgcn_s_setprio(1);
#pragma unroll
        for (int kk = 0; kk < 2; ++kk)
#pragma unroll
          for (int n = 0; n < 4; ++n) {
            bf16x8 kf =
                *reinterpret_cast<const bf16x8*>(&Kl[n * 16 + col][g * 8 + kk * 32]);
            sc[0][n] =
                __builtin_amdgcn_mfma_f32_16x16x32_bf16(kf, qf[0][kk], sc[0][n], 0, 0, 0);
            sc[1][n] =
                __builtin_amdgcn_mfma_f32_16x16x32_bf16(kf, qf[1][kk], sc[1][n], 0, 0, 0);
          }
        __builtin_amdgcn_s_setprio(0);
#pragma unroll
        for (int m = 0; m < 2; ++m) {
          const int q = q0 + wave * 32 + m * 16 + col;
          float pm = -3e38f;
          if (k0 + 63 > q0 + wave * 32 + m * 16) {  // tile touches diagonal
#pragma unroll
            for (int n = 0; n < 4; ++n)
#pragma unroll
              for (int r = 0; r < 4; ++r) {
                int key = k0 + n * 16 + g * 4 + r;
                if (key > q) sc[m][n][r] = -3e38f;
                pm = fmaxf(pm, sc[m][n][r]);
              }
          } else {
#pragma unroll
            for (int n = 0; n < 4; ++n)
#pragma unroll
              for (int r = 0; r < 4; ++r) pm = fmaxf(pm, sc[m][n][r]);
          }
          pm = fmaxf(pm, __shfl_xor(pm, 16));
          pm = fmaxf(pm, __shfl_xor(pm, 32));
          float mnew;
          if (__all(pm <= m_s[m] + 8.0f)) {  // defer-max: no rescale pass
            mnew = m_s[m];
          } else {
            mnew = fmaxf(m_s[m], pm);
            float resc = exp2f(m_s[m] - mnew);
            l_s[m] *= resc;
#pragma unroll
            for (int r = 0; r < 4; ++r) {
              float rr = __shfl(resc, (lane & 48) | (g * 4 + r));
#pragma unroll
              for (int n2 = 0; n2 < 4; ++n2) o[m][n2][r] *= rr;
            }
          }
          float tsum = 0.0f;
#pragma unroll
          for (int n = 0; n < 4; ++n)
#pragma unroll
            for (int r = 0; r < 4; ++r) {
              float p = exp2f(sc[m][n][r] - mnew);
              sc[m][n][r] = p;
              tsum += p;
            }
          tsum += __shfl_xor(tsum, 16);
          tsum += __shfl_xor(tsum, 32);
          l_s[m] += tsum;
          m_s[m] = mnew;
#pragma unroll
          for (int n = 0; n < 4; ++n) {
            alignas(8) bf16 t[4];
#pragma unroll
            for (int r = 0; r < 4; ++r) t[r] = __float2bfloat16(sc[m][n][r]);
            *reinterpret_cast<uint2*>(&QPl[wave * 32 + m * 16 + col][n * 16 + g * 4]) =
                *reinterpret_cast<uint2*>(t);
          }
        }
        // O += P V   (P in wave-private LDS rows)
        __builtin_amdgcn_s_setprio(1);
#pragma unroll
        for (int kk = 0; kk < 2; ++kk) {
          bf16x8 pf0 =
              *reinterpret_cast<const bf16x8*>(&QPl[wave * 32 + col][g * 8 + kk * 32]);
          bf16x8 pf1 = *reinterpret_cast<const bf16x8*>(
              &QPl[wave * 32 + 16 + col][g * 8 + kk * 32]);
#pragma unroll
          for (int n2 = 0; n2 < 4; ++n2) {
            bf16x8 vf =
                *reinterpret_cast<const bf16x8*>(&Vl[n2 * 16 + col][g * 8 + kk * 32]);
            o[0][n2] = __builtin_amdgcn_mfma_f32_16x16x32_bf16(pf0, vf, o[0][n2], 0, 0, 0);
            o[1][n2] = __builtin_amdgcn_mfma_f32_16x16x32_bf16(pf1, vf, o[1][n2], 0, 0, 0);
          }
        }
        __builtin_amdgcn_s_setprio(0);
      }
    }
#pragma unroll
    for (int m = 0; m < 2; ++m)
#pragma unroll
      for (int r = 0; r < 4; ++r) {
        float inv = 1.0f / __shfl(l_s[m], (lane & 48) | (g * 4 + r));
        int s = q0 + wave * 32 + m * 16 + g * 4 + r;
#pragma unroll
        for (int n2 = 0; n2 < 4; ++n2)
          AO[((size_t)(b * 2048 + s) << 10) + h * 64 + n2 * 16 + col] =
              __float2bfloat16(o[m][n2][r] * inv);
      }
  }
}

// ---------------------------------------------------------------- out projection (128x128)
__global__ __launch_bounds__(256) void k_outproj(const bf16* __restrict__ A,
                                                 const bf16* __restrict__ W,
                                                 float* __restrict__ OUT) {
  __shared__ bf16 Al[128 * 32];
  __shared__ bf16 Bl[128 * 32];
  const int tid = threadIdx.x;
  const int wave = tid >> 6, lane = tid & 63, col = lane & 15, g = lane >> 4;
  const int m0 = blockIdx.x * 128, n0 = blockIdx.y * 128;
  const int wrow = (wave >> 1) * 64, wcol = (wave & 1) * 64;
  const bf16* ga = A + (size_t)(m0 + (tid >> 2)) * 1024 + (tid & 3) * 8;
  const bf16* gb = W + (size_t)(n0 + (tid >> 2)) * 1024 + (tid & 3) * 8;
  bf16* la = Al + (tid >> 2) * 32 + (tid & 3) * 8;
  bf16* lb = Bl + (tid >> 2) * 32 + (tid & 3) * 8;
  f32x4 acc[4][4] = {};
  for (int k0 = 0; k0 < 1024; k0 += 32) {
    __syncthreads();
    gload16(ga + k0, la);
    gload16(ga + k0 + 64 * 1024, la + 64 * 32);
    gload16(gb + k0, lb);
    gload16(gb + k0 + 64 * 1024, lb + 64 * 32);
    __syncthreads();
    bf16x8 af[4], bfr[4];
#pragma unroll
    for (int m = 0; m < 4; ++m)
      af[m] = *reinterpret_cast<const bf16x8*>(&Al[(wrow + m * 16 + col) * 32 + g * 8]);
#pragma unroll
    for (int n = 0; n < 4; ++n)
      bfr[n] = *reinterpret_cast<const bf16x8*>(&Bl[(wcol + n * 16 + col) * 32 + g * 8]);
#pragma unroll
    for (int m = 0; m < 4; ++m)
#pragma unroll
      for (int n = 0; n < 4; ++n)
        acc[m][n] =
            __builtin_amdgcn_mfma_f32_16x16x32_bf16(af[m], bfr[n], acc[m][n], 0, 0, 0);
  }
#pragma unroll
  for (int m = 0; m < 4; ++m)
#pragma unroll
    for (int n = 0; n < 4; ++n)
#pragma unroll
      for (int r = 0; r < 4; ++r)
        OUT[(size_t)(m0 + wrow + m * 16 + g * 4 + r) * 1024 + n0 + wcol + n * 16 + col] =
            acc[m][n][r];
}

// ---------------------------------------------------------------- launcher
extern "C" void kernel_launch(void* const* d_in, const int* in_sizes, int n_in,
                              void* d_out, int out_size, void* d_ws, size_t ws_size,
                              hipStream_t stream) {
  const float* x = (const float*)d_in[0];
  const float* wqkv = (const float*)d_in[1];
  const float* wout = (const float*)d_in[2];
  float* out = (float*)d_out;

  char* ws = (char*)d_ws;
  const size_t SZ_X = (size_t)B_ * S_ * D_ * 2;
  const size_t SZ_WQKV = (size_t)3 * D_ * D_ * 2;
  const size_t SZ_WOUT = (size_t)D_ * D_ * 2;
  const size_t SZ_T = (size_t)B_ * H_ * S_ * HD_ * 2;
  bf16* xb = (bf16*)(ws);
  bf16* wqkvb = (bf16*)(ws + SZ_X);
  bf16* woutb = (bf16*)(ws + SZ_X + SZ_WQKV);
  bf16* qws = (bf16*)(ws + SZ_X + SZ_WQKV + SZ_WOUT);
  bf16* kws = (bf16*)(ws + SZ_X + SZ_WQKV + SZ_WOUT + SZ_T);
  bf16* vtws = (bf16*)(ws + SZ_X + SZ_WQKV + SZ_WOUT + 2 * SZ_T);
  bf16* aob = (bf16*)(ws + SZ_X + SZ_WQKV + SZ_WOUT + 3 * SZ_T);

  const int NTOT4 = (NX_ + NW1_ + NW2_) / 4;
  k_cvt3<<<NTOT4 / 256, 256, 0, stream>>>(x, wqkv, wout, xb, wqkvb, woutb);

  k_qkv<<<dim3(64, 24), 256, 0, stream>>>(xb, wqkvb, qws, kws, vtws);
  k_attn<<<dim3(B_ * H_, S_ / 256), 256, 0, stream>>>(qws, kws, vtws, aob);
  k_outproj<<<dim3(64, 8), 256, 0, stream>>>(aob, woutb, out);
}

// Round 5
// 191.847 us; speedup vs baseline: 2.3689x; 1.0783x over previous
//
#include <hip/hip_runtime.h>
#include <hip/hip_bf16.h>

typedef __bf16 bf16x8 __attribute__((ext_vector_type(8)));
typedef float f32x4 __attribute__((ext_vector_type(4)));
typedef __hip_bfloat16 bf16;

#define B_ 4
#define S_ 2048
#define D_ 1024
#define H_ 16
#define HD_ 64

__device__ __forceinline__ void gload16(const bf16* g, bf16* l) {
  __builtin_amdgcn_global_load_lds(
      (const __attribute__((address_space(1))) unsigned int*)g,
      (__attribute__((address_space(3))) unsigned int*)l, 16, 0, 0);
}

// ---------------------------------------------------------------- cvt f32->bf16 (fused x, w_qkv, w_out)
#define NX_ (B_ * S_ * D_)
#define NW1_ (3 * D_ * D_)
#define NW2_ (D_ * D_)
__global__ __launch_bounds__(256) void k_cvt3(const float* __restrict__ x,
                                              const float* __restrict__ w1,
                                              const float* __restrict__ w2,
                                              bf16* __restrict__ ox,
                                              bf16* __restrict__ o1,
                                              bf16* __restrict__ o2) {
  int i = (blockIdx.x * 256 + threadIdx.x) * 4;
  const float* in;
  bf16* out;
  if (i < NX_) {
    in = x; out = ox;
  } else if (i < NX_ + NW1_) {
    in = w1; out = o1; i -= NX_;
  } else {
    in = w2; out = o2; i -= NX_ + NW1_;
  }
  float4 v = *reinterpret_cast<const float4*>(in + i);
  alignas(8) bf16 t[4];
  t[0] = __float2bfloat16(v.x);
  t[1] = __float2bfloat16(v.y);
  t[2] = __float2bfloat16(v.z);
  t[3] = __float2bfloat16(v.w);
  *reinterpret_cast<uint2*>(out + i) = *reinterpret_cast<uint2*>(t);
}

// ---------------------------------------------------------------- QKV GEMM (128x128) + RoPE
// Q gets RoPE and *0.125*log2(e) (softmax runs in exp2 domain). K gets RoPE.
// V stored TRANSPOSED [bh][d][s].
__global__ __launch_bounds__(256) void k_qkv(const bf16* __restrict__ X,
                                             const bf16* __restrict__ W,
                                             bf16* __restrict__ Qw,
                                             bf16* __restrict__ Kw,
                                             bf16* __restrict__ Vtw) {
  __shared__ bf16 Al[128 * 32];
  __shared__ bf16 Bl[128 * 32];
  const int tid = threadIdx.x;
  const int wave = tid >> 6, lane = tid & 63, col = lane & 15, g = lane >> 4;
  const int m0 = blockIdx.x * 128, n0 = blockIdx.y * 128;
  const int wrow = (wave >> 1) * 64, wcol = (wave & 1) * 64;
  const bf16* ga = X + (size_t)(m0 + (tid >> 2)) * 1024 + (tid & 3) * 8;
  const bf16* gb = W + (size_t)(n0 + (tid >> 2)) * 1024 + (tid & 3) * 8;
  bf16* la = Al + (tid >> 2) * 32 + (tid & 3) * 8;
  bf16* lb = Bl + (tid >> 2) * 32 + (tid & 3) * 8;
  f32x4 acc[4][4] = {};
  for (int k0 = 0; k0 < 1024; k0 += 32) {
    __syncthreads();
    gload16(ga + k0, la);
    gload16(ga + k0 + 64 * 1024, la + 64 * 32);
    gload16(gb + k0, lb);
    gload16(gb + k0 + 64 * 1024, lb + 64 * 32);
    __syncthreads();
    bf16x8 af[4], bfr[4];
#pragma unroll
    for (int m = 0; m < 4; ++m)
      af[m] = *reinterpret_cast<const bf16x8*>(&Al[(wrow + m * 16 + col) * 32 + g * 8]);
#pragma unroll
    for (int n = 0; n < 4; ++n)
      bfr[n] = *reinterpret_cast<const bf16x8*>(&Bl[(wcol + n * 16 + col) * 32 + g * 8]);
#pragma unroll
    for (int m = 0; m < 4; ++m)
#pragma unroll
      for (int n = 0; n < 4; ++n)
        acc[m][n] =
            __builtin_amdgcn_mfma_f32_16x16x32_bf16(af[m], bfr[n], acc[m][n], 0, 0, 0);
  }
  const int e0 = n0 + wcol;
  const int which = e0 >> 10;
  const int h = (e0 >> 6) & 15;
  if (which == 2) {
#pragma unroll
    for (int m = 0; m < 4; ++m) {
      int mg = m0 + wrow + m * 16 + g * 4;
      int b = mg >> 11, s = mg & 2047;
#pragma unroll
      for (int n = 0; n < 4; ++n) {
        int d = n * 16 + col;
        alignas(8) bf16 t[4];
#pragma unroll
        for (int r = 0; r < 4; ++r) t[r] = __float2bfloat16(acc[m][n][r]);
        *reinterpret_cast<uint2*>(&Vtw[((size_t)((b * 16 + h) * 64 + d) << 11) + s]) =
            *reinterpret_cast<uint2*>(t);
      }
    }
  } else {
    bf16* dst = which ? Kw : Qw;
    const float scale = which ? 1.0f : 0.18033688011112042f;  // 0.125*log2(e)
    const float fexp = -2.0f * 13.287712379549449f / 64.0f;
#pragma unroll
    for (int i = 0; i < 2; ++i) {
      int dlo = i * 16 + col;
      float invf = exp2f(fexp * (float)dlo);
#pragma unroll
      for (int m = 0; m < 4; ++m) {
        int mg = m0 + wrow + m * 16 + g * 4;
        int b = mg >> 11;
        size_t rb = (size_t)(b * 16 + h) << 11;
#pragma unroll
        for (int r = 0; r < 4; ++r) {
          int s = (mg + r) & 2047;
          float sn, cs;
          __sincosf((float)s * invf, &sn, &cs);
          float lo = acc[m][i][r] * scale, hi = acc[m][i + 2][r] * scale;
          dst[((rb + s) << 6) + dlo] = __float2bfloat16(lo * cs - hi * sn);
          dst[((rb + s) << 6) + dlo + 32] = __float2bfloat16(hi * cs + lo * sn);
        }
      }
    }
  }
}

// ---------------------------------------------------------------- flash attention
// QBLK=128, 512 threads: 8 waves x 16 q-rows (m=1). KVBLK=64. Swapped QK^T
// (lane owns q=col). Diagonal-pair scheduling: block y does qt=y then 15-y
// (exactly 34 tile-units each). 2 blocks/CU x 8 waves = 16 waves/CU.
// Q in regs; Q LDS reused as P buffer. Async-stage K/V via regs (T14).
// Defer-max (T13, THR=8 log2-units).
__global__ __launch_bounds__(512) void k_attn(const bf16* __restrict__ Q,
                                              const bf16* __restrict__ K,
                                              const bf16* __restrict__ Vt,
                                              bf16* __restrict__ AO) {
  __shared__ bf16 QPl[128][72];  // Q staging, then P buffer (wave-private rows)
  __shared__ bf16 Kl[64][72];
  __shared__ bf16 Vl[64][72];  // [d][key]
  const int tid = threadIdx.x;
  const int wave = tid >> 6, lane = tid & 63, col = lane & 15, g = lane >> 4;
  const int bh = blockIdx.x;
  const size_t base = (size_t)bh << 17;
  const int r0 = tid >> 3, c0 = (tid & 7) * 8;  // r0: 0..63
  const int b = bh >> 4, h = bh & 15;
  for (int half = 0; half < 2; ++half) {
    const int qt = half ? (15 - blockIdx.y) : blockIdx.y;
    const int q0 = qt * 128;
    __syncthreads();  // protect QPl (P rows of previous half) before restage
    *reinterpret_cast<int4*>(&QPl[r0][c0]) =
        *reinterpret_cast<const int4*>(&Q[base + (size_t)(q0 + r0) * 64 + c0]);
    *reinterpret_cast<int4*>(&QPl[r0 + 64][c0]) =
        *reinterpret_cast<const int4*>(&Q[base + (size_t)(q0 + r0 + 64) * 64 + c0]);
    __syncthreads();
    bf16x8 qf[2];
#pragma unroll
    for (int kk = 0; kk < 2; ++kk)
      qf[kk] = *reinterpret_cast<const bf16x8*>(&QPl[wave * 16 + col][g * 8 + kk * 32]);
    float m_s = -3e38f, l_s = 0.0f;
    f32x4 o[4] = {};
    const int ktlim = 2 * qt + 1;                  // block-wide last tile (incl.)
    const int ktmax = (q0 + wave * 16 + 15) >> 6;  // this wave's last useful tile
    // prologue: load kt=0 K/V into regs
    int4 kr = *reinterpret_cast<const int4*>(&K[base + (size_t)r0 * 64 + c0]);
    int4 vr = *reinterpret_cast<const int4*>(&Vt[base + (size_t)r0 * 2048 + c0]);
    for (int kt = 0; kt <= ktlim; ++kt) {
      const int k0 = kt * 64;
      __syncthreads();
      *reinterpret_cast<int4*>(&Kl[r0][c0]) = kr;
      *reinterpret_cast<int4*>(&Vl[r0][c0]) = vr;
      __syncthreads();
      if (kt < ktlim) {  // issue next tile's loads; latency hides under compute
        const int k1 = k0 + 64;
        kr = *reinterpret_cast<const int4*>(&K[base + (size_t)(k1 + r0) * 64 + c0]);
        vr = *reinterpret_cast<const int4*>(&Vt[base + (size_t)r0 * 2048 + k1 + c0]);
      }
      if (kt <= ktmax) {
        f32x4 sc[4] = {};
        __builtin_amdgcn_s_setprio(1);
#pragma unroll
        for (int kk = 0; kk < 2; ++kk)
#pragma unroll
          for (int n = 0; n < 4; ++n) {
            bf16x8 kf =
                *reinterpret_cast<const bf16x8*>(&Kl[n * 16 + col][g * 8 + kk * 32]);
            sc[n] = __builtin_amdgcn_mfma_f32_16x16x32_bf16(kf, qf[kk], sc[n], 0, 0, 0);
          }
        __builtin_amdgcn_s_setprio(0);
        const int q = q0 + wave * 16 + col;
        float pm = -3e38f;
        if (k0 + 63 > q0 + wave * 16) {  // wave-uniform: tile touches diagonal
#pragma unroll
          for (int n = 0; n < 4; ++n)
#pragma unroll
            for (int r = 0; r < 4; ++r) {
              int key = k0 + n * 16 + g * 4 + r;
              if (key > q) sc[n][r] = -3e38f;
              pm = fmaxf(pm, sc[n][r]);
            }
        } else {
#pragma unroll
          for (int n = 0; n < 4; ++n)
#pragma unroll
            for (int r = 0; r < 4; ++r) pm = fmaxf(pm, sc[n][r]);
        }
        pm = fmaxf(pm, __shfl_xor(pm, 16));
        pm = fmaxf(pm, __shfl_xor(pm, 32));
        float mnew;
        if (__all(pm <= m_s + 8.0f)) {  // defer-max: skip rescale pass
          mnew = m_s;
        } else {
          mnew = fmaxf(m_s, pm);
          float resc = exp2f(m_s - mnew);
          l_s *= resc;
#pragma unroll
          for (int r = 0; r < 4; ++r) {
            float rr = __shfl(resc, (lane & 48) | (g * 4 + r));
#pragma unroll
            for (int n2 = 0; n2 < 4; ++n2) o[n2][r] *= rr;
          }
        }
        float tsum = 0.0f;
#pragma unroll
        for (int n = 0; n < 4; ++n)
#pragma unroll
          for (int r = 0; r < 4; ++r) {
            float p = exp2f(sc[n][r] - mnew);
            sc[n][r] = p;
            tsum += p;
          }
        tsum += __shfl_xor(tsum, 16);
        tsum += __shfl_xor(tsum, 32);
        l_s += tsum;
        m_s = mnew;
#pragma unroll
        for (int n = 0; n < 4; ++n) {
          alignas(8) bf16 t[4];
#pragma unroll
          for (int r = 0; r < 4; ++r) t[r] = __float2bfloat16(sc[n][r]);
          *reinterpret_cast<uint2*>(&QPl[wave * 16 + col][n * 16 + g * 4]) =
              *reinterpret_cast<uint2*>(t);
        }
        // O += P V   (P in wave-private LDS rows)
        __builtin_amdgcn_s_setprio(1);
#pragma unroll
        for (int kk = 0; kk < 2; ++kk) {
          bf16x8 pf =
              *reinterpret_cast<const bf16x8*>(&QPl[wave * 16 + col][g * 8 + kk * 32]);
#pragma unroll
          for (int n2 = 0; n2 < 4; ++n2) {
            bf16x8 vf =
                *reinterpret_cast<const bf16x8*>(&Vl[n2 * 16 + col][g * 8 + kk * 32]);
            o[n2] = __builtin_amdgcn_mfma_f32_16x16x32_bf16(pf, vf, o[n2], 0, 0, 0);
          }
        }
        __builtin_amdgcn_s_setprio(0);
      }
    }
#pragma unroll
    for (int r = 0; r < 4; ++r) {
      float inv = 1.0f / __shfl(l_s, (lane & 48) | (g * 4 + r));
      int s = q0 + wave * 16 + g * 4 + r;
#pragma unroll
      for (int n2 = 0; n2 < 4; ++n2)
        AO[((size_t)(b * 2048 + s) << 10) + h * 64 + n2 * 16 + col] =
            __float2bfloat16(o[n2][r] * inv);
    }
  }
}

// ---------------------------------------------------------------- out projection (128x128)
__global__ __launch_bounds__(256) void k_outproj(const bf16* __restrict__ A,
                                                 const bf16* __restrict__ W,
                                                 float* __restrict__ OUT) {
  __shared__ bf16 Al[128 * 32];
  __shared__ bf16 Bl[128 * 32];
  const int tid = threadIdx.x;
  const int wave = tid >> 6, lane = tid & 63, col = lane & 15, g = lane >> 4;
  const int m0 = blockIdx.x * 128, n0 = blockIdx.y * 128;
  const int wrow = (wave >> 1) * 64, wcol = (wave & 1) * 64;
  const bf16* ga = A + (size_t)(m0 + (tid >> 2)) * 1024 + (tid & 3) * 8;
  const bf16* gb = W + (size_t)(n0 + (tid >> 2)) * 1024 + (tid & 3) * 8;
  bf16* la = Al + (tid >> 2) * 32 + (tid & 3) * 8;
  bf16* lb = Bl + (tid >> 2) * 32 + (tid & 3) * 8;
  f32x4 acc[4][4] = {};
  for (int k0 = 0; k0 < 1024; k0 += 32) {
    __syncthreads();
    gload16(ga + k0, la);
    gload16(ga + k0 + 64 * 1024, la + 64 * 32);
    gload16(gb + k0, lb);
    gload16(gb + k0 + 64 * 1024, lb + 64 * 32);
    __syncthreads();
    bf16x8 af[4], bfr[4];
#pragma unroll
    for (int m = 0; m < 4; ++m)
      af[m] = *reinterpret_cast<const bf16x8*>(&Al[(wrow + m * 16 + col) * 32 + g * 8]);
#pragma unroll
    for (int n = 0; n < 4; ++n)
      bfr[n] = *reinterpret_cast<const bf16x8*>(&Bl[(wcol + n * 16 + col) * 32 + g * 8]);
#pragma unroll
    for (int m = 0; m < 4; ++m)
#pragma unroll
      for (int n = 0; n < 4; ++n)
        acc[m][n] =
            __builtin_amdgcn_mfma_f32_16x16x32_bf16(af[m], bfr[n], acc[m][n], 0, 0, 0);
  }
#pragma unroll
  for (int m = 0; m < 4; ++m)
#pragma unroll
    for (int n = 0; n < 4; ++n)
#pragma unroll
      for (int r = 0; r < 4; ++r)
        OUT[(size_t)(m0 + wrow + m * 16 + g * 4 + r) * 1024 + n0 + wcol + n * 16 + col] =
            acc[m][n][r];
}

// ---------------------------------------------------------------- launcher
extern "C" void kernel_launch(void* const* d_in, const int* in_sizes, int n_in,
                              void* d_out, int out_size, void* d_ws, size_t ws_size,
                              hipStream_t stream) {
  const float* x = (const float*)d_in[0];
  const float* wqkv = (const float*)d_in[1];
  const float* wout = (const float*)d_in[2];
  float* out = (float*)d_out;

  char* ws = (char*)d_ws;
  const size_t SZ_X = (size_t)B_ * S_ * D_ * 2;
  const size_t SZ_WQKV = (size_t)3 * D_ * D_ * 2;
  const size_t SZ_WOUT = (size_t)D_ * D_ * 2;
  const size_t SZ_T = (size_t)B_ * H_ * S_ * HD_ * 2;
  bf16* xb = (bf16*)(ws);
  bf16* wqkvb = (bf16*)(ws + SZ_X);
  bf16* woutb = (bf16*)(ws + SZ_X + SZ_WQKV);
  bf16* qws = (bf16*)(ws + SZ_X + SZ_WQKV + SZ_WOUT);
  bf16* kws = (bf16*)(ws + SZ_X + SZ_WQKV + SZ_WOUT + SZ_T);
  bf16* vtws = (bf16*)(ws + SZ_X + SZ_WQKV + SZ_WOUT + 2 * SZ_T);
  bf16* aob = (bf16*)(ws + SZ_X + SZ_WQKV + SZ_WOUT + 3 * SZ_T);

  const int NTOT4 = (NX_ + NW1_ + NW2_) / 4;
  k_cvt3<<<NTOT4 / 256, 256, 0, stream>>>(x, wqkv, wout, xb, wqkvb, woutb);

  k_qkv<<<dim3(64, 24), 256, 0, stream>>>(xb, wqkvb, qws, kws, vtws);
  k_attn<<<dim3(B_ * H_, 8), 512, 0, stream>>>(qws, kws, vtws, aob);
  k_outproj<<<dim3(64, 8), 256, 0, stream>>>(aob, woutb, out);
}